// Round 5
// baseline (592.206 us; speedup 1.0000x reference)
//
#include <hip/hip_runtime.h>

typedef _Float16 half8 __attribute__((ext_vector_type(8)));
typedef _Float16 half2v __attribute__((ext_vector_type(2)));
typedef float floatx4 __attribute__((ext_vector_type(4)));

#define K_IN 4096
#define N_OUT 4096
#define NGROUPS 32

__device__ __forceinline__ unsigned int pkcvt(float lo, float hi) {
    // v_cvt_pkrtz_f16_f32: element0 <- lo, element1 <- hi (fp16-origin fp32 -> exact)
    return __builtin_bit_cast(unsigned int, __builtin_amdgcn_cvt_pkrtz(lo, hi));
}

// async global->LDS, 16 B per lane; LDS dest = wave-uniform base + lane*16
__device__ __forceinline__ void gll16(const _Float16* g, _Float16* l) {
    __builtin_amdgcn_global_load_lds(
        (const __attribute__((address_space(1))) void*)g,
        (__attribute__((address_space(3))) void*)l, 16, 0, 0);
}

// ---------------- pass 1: x fp32 -> fp16, natural layout [M][K] ----------------
__global__ __launch_bounds__(256)
void cvt_x_f16(const float* __restrict__ x, _Float16* __restrict__ x16) {
    const size_t idx = ((size_t)blockIdx.x * 256 + threadIdx.x) * 8;
    const float4 a = *(const float4*)(x + idx);
    const float4 b = *(const float4*)(x + idx + 4);
    uint4 u;
    u.x = pkcvt(a.x, a.y);  u.y = pkcvt(a.z, a.w);
    u.z = pkcvt(b.x, b.y);  u.w = pkcvt(b.z, b.w);
    *(uint4*)(x16 + idx) = u;
}

// ---------------- pass 2: dequant qweight -> Wt fp16 [N][K] (transposed) -------
__global__ __launch_bounds__(256)
void dequant_wt(const int* __restrict__ qweight,  // [K/8, N]
                const int* __restrict__ qzeros,   // [G, N/8]
                const float* __restrict__ scales, // [G, N]
                _Float16* __restrict__ wt)        // [N, K]
{
    const int tid = threadIdx.x;
    const int col = blockIdx.x * 64 + (tid & 63);
    const int g   = blockIdx.y;
    const int i   = tid >> 6;

    const unsigned int zw = (unsigned int)qzeros[g * (N_OUT / 8) + (col >> 3)];
    const unsigned int z  = (zw >> ((col & 7) * 4)) & 0xFu;
    const unsigned int cb = 0x6400u + z + 1u;     // f16 bits of 1024+(z+1), exact
    const half2v c2 = __builtin_bit_cast(half2v, cb | (cb << 16));
    const float  s  = scales[g * N_OUT + col];
    const half2v s2 = __builtin_bit_cast(half2v, pkcvt(s, s));

    const int kc0 = g * 16 + i * 4;
#pragma unroll
    for (int r = 0; r < 4; ++r) {
        const unsigned int q = (unsigned int)qweight[(size_t)(kc0 + r) * N_OUT + col];
        const unsigned int r0 = (q & 0x000F000Fu)         | 0x64006400u; // (k0,k4)
        const unsigned int r1 = ((q >> 4) & 0x000F000Fu)  | 0x64006400u; // (k1,k5)
        const unsigned int r2 = ((q >> 8) & 0x000F000Fu)  | 0x64006400u; // (k2,k6)
        const unsigned int r3 = ((q >> 12) & 0x000F000Fu) | 0x64006400u; // (k3,k7)
        unsigned int p0 = __builtin_bit_cast(unsigned int,
                          (half2v)((__builtin_bit_cast(half2v, r0) - c2) * s2));
        unsigned int p1 = __builtin_bit_cast(unsigned int,
                          (half2v)((__builtin_bit_cast(half2v, r1) - c2) * s2));
        unsigned int p2 = __builtin_bit_cast(unsigned int,
                          (half2v)((__builtin_bit_cast(half2v, r2) - c2) * s2));
        unsigned int p3 = __builtin_bit_cast(unsigned int,
                          (half2v)((__builtin_bit_cast(half2v, r3) - c2) * s2));
        uint4 nat;
        nat.x = (p0 & 0xFFFFu) | (p1 << 16);          // (k0,k1)
        nat.y = (p2 & 0xFFFFu) | (p3 << 16);          // (k2,k3)
        nat.z = (p0 >> 16) | (p1 & 0xFFFF0000u);      // (k4,k5)
        nat.w = (p2 >> 16) | (p3 & 0xFFFF0000u);      // (k6,k7)
        *(uint4*)(wt + (size_t)col * K_IN + (kc0 + r) * 8) = nat;
    }
}

// ---------------- pass 3: fp16 GEMM, 256x256 8-phase counted-vmcnt ------------
// 8 waves (2M x 4N), per-wave 128x64 out, BK=64, LDS 128 KiB (A,B double-buf).
// LDS layout per operand: [buf][row 0..255][k 0..63] f16, rows = 128 B; logical
// 16B-chunk c of row r stored at physical chunk c ^ (r&7) (zero-conflict
// involution verified r3/r4, extended to 8-chunk rows). gll dest linear,
// source pre-swizzled; ds_read applies the same XOR.
// Schedule per iteration (2 K-tiles): P0-3 compute kt (buf0) / stage kt+1->buf1
// one half-tile per phase; P4-7 compute kt+1 (buf1) / stage kt+2->buf0.
// vmcnt(2) + barrier only at P0/P4 (drains exactly the opening buffer's 8
// loads; the 2 just-issued stay in flight). Never vmcnt(0) in the loop.

#define BARRIER() asm volatile("s_barrier" ::: "memory")
#define VMCNT2()  asm volatile("s_waitcnt vmcnt(2)" ::: "memory")

// stage one half-tile (128 rows x 64 k) of op into buf d: 2 gll16 per thread
#define STAGE_A(d, half, kt)                                                   \
    do {                                                                       \
        gll16(aS + (size_t)((half) * 128) * K_IN + (kt) * 64,                  \
              ashW + (d) * 16384 + (half) * 8192);                             \
        gll16(aS + (size_t)((half) * 128 + 64) * K_IN + (kt) * 64,             \
              ashW + (d) * 16384 + (half) * 8192 + 4096);                      \
    } while (0)
#define STAGE_B(d, half, kt)                                                   \
    do {                                                                       \
        gll16(bS + (size_t)((half) * 128) * K_IN + (kt) * 64,                  \
              bshW + (d) * 16384 + (half) * 8192);                             \
        gll16(bS + (size_t)((half) * 128 + 64) * K_IN + (kt) * 64,             \
              bshW + (d) * 16384 + (half) * 8192 + 4096);                      \
    } while (0)

// one phase: 12 ds_read_b128 (quadrant q of buf d) | STAGE_STMT | MID | 16 MFMA
#define PH_BODY(d, q, STAGE_STMT, MID_BARRIER)                                 \
    {                                                                          \
        const int dbase = (d) * 16384;                                         \
        half8 af[4][2]; half8 bf[2][2];                                        \
        _Pragma("unroll")                                                      \
        for (int m = 0; m < 4; ++m) {                                          \
            const int ro = dbase + aRow + (((q) & 1) * 4 + m) * 1024;          \
            af[m][0] = *(const half8*)(const void*)&Ash[ro + c0];              \
            af[m][1] = *(const half8*)(const void*)&Ash[ro + (c0 ^ 32)];       \
        }                                                                      \
        _Pragma("unroll")                                                      \
        for (int n = 0; n < 2; ++n) {                                          \
            const int ro = dbase + bRow + (((q) >> 1) * 2 + n) * 1024;         \
            bf[n][0] = *(const half8*)(const void*)&Bsh[ro + c0];              \
            bf[n][1] = *(const half8*)(const void*)&Bsh[ro + (c0 ^ 32)];       \
        }                                                                      \
        STAGE_STMT;                                                            \
        MID_BARRIER;                                                           \
        __builtin_amdgcn_s_setprio(1);                                         \
        _Pragma("unroll")                                                      \
        for (int m = 0; m < 4; ++m)                                            \
            _Pragma("unroll")                                                  \
            for (int n = 0; n < 2; ++n) {                                      \
                acc[((q) & 1) * 4 + m][((q) >> 1) * 2 + n] =                   \
                    __builtin_amdgcn_mfma_f32_16x16x32_f16(                    \
                        af[m][0], bf[n][0],                                    \
                        acc[((q) & 1) * 4 + m][((q) >> 1) * 2 + n], 0, 0, 0);  \
                acc[((q) & 1) * 4 + m][((q) >> 1) * 2 + n] =                   \
                    __builtin_amdgcn_mfma_f32_16x16x32_f16(                    \
                        af[m][1], bf[n][1],                                    \
                        acc[((q) & 1) * 4 + m][((q) >> 1) * 2 + n], 0, 0, 0);  \
            }                                                                  \
        __builtin_amdgcn_s_setprio(0);                                         \
        BARRIER();                                                             \
    }

__global__ __launch_bounds__(512, 2)
void gemm_f16_8ph(const _Float16* __restrict__ x16,  // [M,K] f16
                  const _Float16* __restrict__ wt,   // [N,K] f16
                  const float* __restrict__ bias,    // [N] f32
                  float* __restrict__ out)           // [M,N] f32
{
    __shared__ alignas(16) _Float16 Ash[2 * 256 * 64];   // 64 KiB
    __shared__ alignas(16) _Float16 Bsh[2 * 256 * 64];   // 64 KiB

    const int tid  = threadIdx.x;        // 0..511
    const int lane = tid & 63;
    const int wave = tid >> 6;           // 0..7
    const int wm   = wave >> 2;          // 0..1 : M half (128 rows)
    const int wn   = wave & 3;           // 0..3 : N quarter (64 cols)
    const int l15  = lane & 15;
    const int l4   = lane >> 4;

    // bijective XCD swizzle (nwg % 8 == 0): each XCD gets a contiguous chunk,
    // n-fast within chunk -> A-panel (2 MB) reused 16x in the XCD's L2.
    const int nwg = gridDim.x;
    const int lin = blockIdx.x;
    const int wg  = (lin & 7) * (nwg >> 3) + (lin >> 3);
    const int blockN = (wg & 15) * 256;
    const int blockM = (wg >> 4) * 256;

    floatx4 acc[8][4] = {};

    // ---- staging geometry: thread t covers row r*64 + (t>>3), phys chunk t&7,
    //      logical chunk (t&7)^((t>>3)&7)  (row&7 == (t>>3)&7) ----
    const int srow = tid >> 3;                         // 0..63
    const int lchk = (tid & 7) ^ ((tid >> 3) & 7);
    const _Float16* aS = x16 + (size_t)(blockM + srow) * K_IN + lchk * 8;
    const _Float16* bS = wt  + (size_t)(blockN + srow) * K_IN + lchk * 8;
    _Float16* ashW = &Ash[wave * 512];                 // wave-uniform dest base
    _Float16* bshW = &Bsh[wave * 512];

    // ---- ds_read geometry: frag (row = base + l15, logical chunk s*4 + l4),
    //      phys chunk = (s*4 + l4) ^ (l15&7); elem offset c0 (s=0), c0^32 (s=1)
    const int aRow = (wm * 128 + l15) * 64;
    const int bRow = (wn * 64 + l15) * 64;
    const int c0   = (l4 ^ (l15 & 7)) * 8;

    // ---- prologue: stage kt=0 fully into buf0 (8 loads) ----
    STAGE_A(0, 0, 0);
    STAGE_A(0, 1, 0);
    STAGE_B(0, 0, 0);
    STAGE_B(0, 1, 0);

    for (int i = 0; i < 32; ++i) {
        const int kt1 = 2 * i + 1;
        const int kt2 = (2 * i + 2 < 64) ? 2 * i + 2 : 63;  // clamped restage

        // P0 (sync): open buf0; stage kt1-A0 -> buf1
        STAGE_A(1, 0, kt1);
        VMCNT2();
        BARRIER();
        PH_BODY(0, 0, (void)0, (void)0)
        // P1..P3: compute buf0 q1..q3; stage kt1 A1,B0,B1 -> buf1
        PH_BODY(0, 1, STAGE_A(1, 1, kt1), BARRIER())
        PH_BODY(0, 2, STAGE_B(1, 0, kt1), BARRIER())
        PH_BODY(0, 3, STAGE_B(1, 1, kt1), BARRIER())
        // P4 (sync): open buf1; stage kt2-A0 -> buf0
        STAGE_A(0, 0, kt2);
        VMCNT2();
        BARRIER();
        PH_BODY(1, 0, (void)0, (void)0)
        // P5..P7: compute buf1 q1..q3; stage kt2 A1,B0,B1 -> buf0
        PH_BODY(1, 1, STAGE_A(0, 1, kt2), BARRIER())
        PH_BODY(1, 2, STAGE_B(0, 0, kt2), BARRIER())
        PH_BODY(1, 3, STAGE_B(0, 1, kt2), BARRIER())
    }

    // ---- epilogue: C frag layout col=lane&15, row=(lane>>4)*4+reg ----
#pragma unroll
    for (int n = 0; n < 4; ++n) {
        const int col = blockN + wn * 64 + n * 16 + l15;
        const float bv = bias[col];
#pragma unroll
        for (int m = 0; m < 8; ++m) {
            const int row = blockM + wm * 128 + m * 16 + l4 * 4;
#pragma unroll
            for (int r = 0; r < 4; ++r)
                out[(size_t)(row + r) * N_OUT + col] = acc[m][n][r] + bv;
        }
    }
}

// ---------------- fallback: verified fused kernel (ws too small) --------------
#define BM 128
#define BN 128
__global__ __launch_bounds__(256, 2)
void gptq_gemm_fused(const float* __restrict__ x,
                     const int*   __restrict__ qweight,
                     const int*   __restrict__ qzeros,
                     const float* __restrict__ scales,
                     const float* __restrict__ bias,
                     float*       __restrict__ out)
{
#define LDA 40
    __shared__ alignas(16) _Float16 Asf[2][BM * LDA];

    const int tid  = threadIdx.x;
    const int lane = tid & 63;
    const int wave = tid >> 6;
    const int l15  = lane & 15;
    const int l4   = lane >> 4;

    const int blockN = blockIdx.x * BN;
    const int blockM = blockIdx.y * BM;

    floatx4 acc[8][2] = {};

    const int srow = tid >> 2;
    const int sch  = tid & 3;
    const float* xr0 = x + (size_t)(blockM + srow) * K_IN + sch * 8;
    const float* xr1 = xr0 + (size_t)64 * K_IN;
    _Float16* lw0 = &Asf[0][srow * LDA + sch * 8];
    _Float16* lw1 = &Asf[0][(srow + 64) * LDA + sch * 8];

    int ncol[2];
#pragma unroll
    for (int j = 0; j < 2; ++j) ncol[j] = blockN + wave * 32 + j * 16 + l15;

    unsigned int zraw[2]; float sraw[2];
#pragma unroll
    for (int j = 0; j < 2; ++j) {
        zraw[j] = (unsigned int)qzeros[ncol[j] >> 3];
        sraw[j] = scales[ncol[j]];
    }
    float4 pa0 = *(const float4*)(xr0);
    float4 pa1 = *(const float4*)(xr0 + 4);
    float4 pb0 = *(const float4*)(xr1);
    float4 pb1 = *(const float4*)(xr1 + 4);
    unsigned int pq[2];
    {
        const int* qr = qweight + (size_t)l4 * N_OUT;
#pragma unroll
        for (int j = 0; j < 2; ++j) pq[j] = (unsigned int)qr[ncol[j]];
    }

    for (int g = 0; g < NGROUPS; ++g) {
        unsigned int c2u[2], s2u[2];
#pragma unroll
        for (int j = 0; j < 2; ++j) {
            const unsigned int z  = (zraw[j] >> ((ncol[j] & 7) * 4)) & 0xFu;
            const unsigned int cb = 0x6400u + z + 1u;
            c2u[j] = cb | (cb << 16);
            s2u[j] = pkcvt(sraw[j], sraw[j]);
        }
        const int gn = (g + 1 < NGROUPS) ? g + 1 : g;
#pragma unroll
        for (int j = 0; j < 2; ++j) {
            zraw[j] = (unsigned int)qzeros[gn * (N_OUT / 8) + (ncol[j] >> 3)];
            sraw[j] = scales[gn * N_OUT + ncol[j]];
        }

#pragma unroll
        for (int kk = 0; kk < 4; ++kk) {
            const int t   = g * 4 + kk;
            const int buf = t & 1;

            uint4 ra, rb;
            ra.x = pkcvt(pa0.x, pa1.x);  ra.y = pkcvt(pa0.y, pa1.y);
            ra.z = pkcvt(pa0.z, pa1.z);  ra.w = pkcvt(pa0.w, pa1.w);
            rb.x = pkcvt(pb0.x, pb1.x);  rb.y = pkcvt(pb0.y, pb1.y);
            rb.z = pkcvt(pb0.z, pb1.z);  rb.w = pkcvt(pb0.w, pb1.w);
            *(uint4*)(void*)(lw0 + buf * (BM * LDA)) = ra;
            *(uint4*)(void*)(lw1 + buf * (BM * LDA)) = rb;

            unsigned int bq[2] = {pq[0], pq[1]};

            const int t1 = (t + 1 < 4 * NGROUPS) ? t + 1 : t;
            pa0 = *(const float4*)(xr0 + t1 * 32);
            pa1 = *(const float4*)(xr0 + t1 * 32 + 4);
            pb0 = *(const float4*)(xr1 + t1 * 32);
            pb1 = *(const float4*)(xr1 + t1 * 32 + 4);
            {
                const int* qr = qweight + (size_t)(t1 * 4 + l4) * N_OUT;
#pragma unroll
                for (int j = 0; j < 2; ++j) pq[j] = (unsigned int)qr[ncol[j]];
            }

            __syncthreads();

            half8 bfrag[2];
#pragma unroll
            for (int j = 0; j < 2; ++j) {
                const unsigned int q = bq[j];
                const unsigned int r0 = (q & 0x000F000Fu)        | 0x64006400u;
                const unsigned int r1 = ((q >> 4) & 0x000F000Fu) | 0x64006400u;
                const unsigned int r2 = ((q >> 8) & 0x000F000Fu) | 0x64006400u;
                const unsigned int r3 = ((q >> 12) & 0x000F000Fu)| 0x64006400u;
                const half2v c2 = __builtin_bit_cast(half2v, c2u[j]);
                const half2v s2 = __builtin_bit_cast(half2v, s2u[j]);
                union { unsigned int u[4]; half8 h; } pk;
                pk.u[0] = __builtin_bit_cast(unsigned int,
                          (half2v)((__builtin_bit_cast(half2v, r0) - c2) * s2));
                pk.u[1] = __builtin_bit_cast(unsigned int,
                          (half2v)((__builtin_bit_cast(half2v, r1) - c2) * s2));
                pk.u[2] = __builtin_bit_cast(unsigned int,
                          (half2v)((__builtin_bit_cast(half2v, r2) - c2) * s2));
                pk.u[3] = __builtin_bit_cast(unsigned int,
                          (half2v)((__builtin_bit_cast(half2v, r3) - c2) * s2));
                bfrag[j] = pk.h;
            }

            half8 afrag[8];
#pragma unroll
            for (int i = 0; i < 8; ++i)
                afrag[i] = *(const half8*)(const void*)
                    &Asf[buf][(i * 16 + l15) * LDA + l4 * 8];

#pragma unroll
            for (int i = 0; i < 8; ++i)
#pragma unroll
                for (int j = 0; j < 2; ++j)
                    acc[i][j] = __builtin_amdgcn_mfma_f32_16x16x32_f16(
                        afrag[i], bfrag[j], acc[i][j], 0, 0, 0);
        }
    }

#pragma unroll
    for (int j = 0; j < 2; ++j) {
        const int n = ncol[j];
        const float bv = bias[n];
#pragma unroll
        for (int i = 0; i < 8; ++i) {
            const int m = blockM + i * 16 + l4 * 4;
#pragma unroll
            for (int r = 0; r < 4; ++r)
                out[(size_t)(m + r) * N_OUT + n] = acc[i][j][r] + bv;
        }
    }
#undef LDA
}

extern "C" void kernel_launch(void* const* d_in, const int* in_sizes, int n_in,
                              void* d_out, int out_size, void* d_ws, size_t ws_size,
                              hipStream_t stream) {
    const float* x    = (const float*)d_in[0];
    const int*   qw   = (const int*)d_in[1];
    const int*   qz   = (const int*)d_in[2];
    const float* sc   = (const float*)d_in[3];
    const float* bias = (const float*)d_in[4];
    float*       out  = (float*)d_out;

    const int M = in_sizes[0] / K_IN;   // 8192

    const size_t x16_bytes = (size_t)M * K_IN * sizeof(_Float16);
    const size_t wt_bytes  = (size_t)N_OUT * K_IN * sizeof(_Float16);

    if (ws_size >= x16_bytes + wt_bytes && (M % 256) == 0) {
        _Float16* x16 = (_Float16*)d_ws;
        _Float16* wtp = (_Float16*)((char*)d_ws + x16_bytes);

        cvt_x_f16<<<(int)((size_t)M * K_IN / 2048), 256, 0, stream>>>(x, x16);
        dequant_wt<<<dim3(N_OUT / 64, NGROUPS), 256, 0, stream>>>(qw, qz, sc, wtp);
        const int nwg = (M / 256) * (N_OUT / 256);   // 512; % 8 == 0
        gemm_f16_8ph<<<nwg, 512, 0, stream>>>(x16, wtp, bias, out);
    } else {
        gptq_gemm_fused<<<dim3(N_OUT / BN, M / BM), 256, 0, stream>>>(
            x, qw, qz, sc, bias, out);
    }
}

// Round 6
// 545.314 us; speedup vs baseline: 1.0860x; 1.0860x over previous
//
#include <hip/hip_runtime.h>

typedef _Float16 half8 __attribute__((ext_vector_type(8)));
typedef _Float16 half2v __attribute__((ext_vector_type(2)));
typedef float floatx4 __attribute__((ext_vector_type(4)));

#define K_IN 4096
#define N_OUT 4096
#define NGROUPS 32

__device__ __forceinline__ unsigned int pkcvt(float lo, float hi) {
    // v_cvt_pkrtz_f16_f32: element0 <- lo, element1 <- hi (fp16-origin fp32 -> exact)
    return __builtin_bit_cast(unsigned int, __builtin_amdgcn_cvt_pkrtz(lo, hi));
}

// async global->LDS, 16 B per lane; LDS dest = wave-uniform base + lane*16
__device__ __forceinline__ void gll16(const _Float16* g, _Float16* l) {
    __builtin_amdgcn_global_load_lds(
        (const __attribute__((address_space(1))) void*)g,
        (__attribute__((address_space(3))) void*)l, 16, 0, 0);
}

// ---------------- pass 1: x fp32 -> fp16, natural layout [M][K] ----------------
__global__ __launch_bounds__(256)
void cvt_x_f16(const float* __restrict__ x, _Float16* __restrict__ x16) {
    const size_t idx = ((size_t)blockIdx.x * 256 + threadIdx.x) * 8;
    const float4 a = *(const float4*)(x + idx);
    const float4 b = *(const float4*)(x + idx + 4);
    uint4 u;
    u.x = pkcvt(a.x, a.y);  u.y = pkcvt(a.z, a.w);
    u.z = pkcvt(b.x, b.y);  u.w = pkcvt(b.z, b.w);
    *(uint4*)(x16 + idx) = u;
}

// ---------------- pass 2: dequant qweight -> Wt fp16 [N][K] (transposed) -------
__global__ __launch_bounds__(256)
void dequant_wt(const int* __restrict__ qweight,  // [K/8, N]
                const int* __restrict__ qzeros,   // [G, N/8]
                const float* __restrict__ scales, // [G, N]
                _Float16* __restrict__ wt)        // [N, K]
{
    const int tid = threadIdx.x;
    const int col = blockIdx.x * 64 + (tid & 63);
    const int g   = blockIdx.y;
    const int i   = tid >> 6;

    const unsigned int zw = (unsigned int)qzeros[g * (N_OUT / 8) + (col >> 3)];
    const unsigned int z  = (zw >> ((col & 7) * 4)) & 0xFu;
    const unsigned int cb = 0x6400u + z + 1u;     // f16 bits of 1024+(z+1), exact
    const half2v c2 = __builtin_bit_cast(half2v, cb | (cb << 16));
    const float  s  = scales[g * N_OUT + col];
    const half2v s2 = __builtin_bit_cast(half2v, pkcvt(s, s));

    const int kc0 = g * 16 + i * 4;
#pragma unroll
    for (int r = 0; r < 4; ++r) {
        const unsigned int q = (unsigned int)qweight[(size_t)(kc0 + r) * N_OUT + col];
        const unsigned int r0 = (q & 0x000F000Fu)         | 0x64006400u; // (k0,k4)
        const unsigned int r1 = ((q >> 4) & 0x000F000Fu)  | 0x64006400u; // (k1,k5)
        const unsigned int r2 = ((q >> 8) & 0x000F000Fu)  | 0x64006400u; // (k2,k6)
        const unsigned int r3 = ((q >> 12) & 0x000F000Fu) | 0x64006400u; // (k3,k7)
        unsigned int p0 = __builtin_bit_cast(unsigned int,
                          (half2v)((__builtin_bit_cast(half2v, r0) - c2) * s2));
        unsigned int p1 = __builtin_bit_cast(unsigned int,
                          (half2v)((__builtin_bit_cast(half2v, r1) - c2) * s2));
        unsigned int p2 = __builtin_bit_cast(unsigned int,
                          (half2v)((__builtin_bit_cast(half2v, r2) - c2) * s2));
        unsigned int p3 = __builtin_bit_cast(unsigned int,
                          (half2v)((__builtin_bit_cast(half2v, r3) - c2) * s2));
        uint4 nat;
        nat.x = (p0 & 0xFFFFu) | (p1 << 16);          // (k0,k1)
        nat.y = (p2 & 0xFFFFu) | (p3 << 16);          // (k2,k3)
        nat.z = (p0 >> 16) | (p1 & 0xFFFF0000u);      // (k4,k5)
        nat.w = (p2 >> 16) | (p3 & 0xFFFF0000u);      // (k6,k7)
        *(uint4*)(wt + (size_t)col * K_IN + (kc0 + r) * 8) = nat;
    }
}

// ---------------- pass 3: fp16 GEMM, 256x256 8-phase, zigzag frag reuse -------
// 8 waves (2M x 4N), per-wave 128x64 out, BK=64, LDS 128 KiB (A,B double-buf).
// Zigzag quadrant order per K-tile: (0,0)->(0,1)->(1,1)->(1,0); frags held in
// registers across phases -> 24 ds_read_b128 per wave per K-tile (the minimum),
// vs 48 with per-quadrant reload (r5's measured LDS pole).
// vmcnt(2) at each buffer open drains exactly the 8 gll of the opening buffer;
// the 2 just-issued stay in flight. Never vmcnt(0) in the loop.

#define BARRIER() asm volatile("s_barrier" ::: "memory")
#define VMCNT2()  asm volatile("s_waitcnt vmcnt(2)" ::: "memory")

// stage one half-tile (128 rows x 64 k) of op into buf d: 2 gll16 per thread
#define STAGE_A(d, half, kt)                                                   \
    do {                                                                       \
        gll16(aS + (size_t)((half) * 128) * K_IN + (kt) * 64,                  \
              ashW + (d) * 16384 + (half) * 8192);                             \
        gll16(aS + (size_t)((half) * 128 + 64) * K_IN + (kt) * 64,             \
              ashW + (d) * 16384 + (half) * 8192 + 4096);                      \
    } while (0)
#define STAGE_B(d, half, kt)                                                   \
    do {                                                                       \
        gll16(bS + (size_t)((half) * 128) * K_IN + (kt) * 64,                  \
              bshW + (d) * 16384 + (half) * 8192);                             \
        gll16(bS + (size_t)((half) * 128 + 64) * K_IN + (kt) * 64,             \
              bshW + (d) * 16384 + (half) * 8192 + 4096);                      \
    } while (0)

// fragment loads (swizzled read, zero-conflict involution verified r3/r4/r5)
#define RD_A(AF, dbase, mh)                                                    \
    _Pragma("unroll")                                                          \
    for (int m = 0; m < 4; ++m) {                                              \
        const int ro = (dbase) + aRow + ((mh) * 4 + m) * 1024;                 \
        AF[m][0] = *(const half8*)(const void*)&Ash[ro + c0];                  \
        AF[m][1] = *(const half8*)(const void*)&Ash[ro + (c0 ^ 32)];           \
    }
#define RD_B(BF, dbase, nh)                                                    \
    _Pragma("unroll")                                                          \
    for (int n = 0; n < 2; ++n) {                                              \
        const int ro = (dbase) + bRow + ((nh) * 2 + n) * 1024;                 \
        BF[n][0] = *(const half8*)(const void*)&Bsh[ro + c0];                  \
        BF[n][1] = *(const half8*)(const void*)&Bsh[ro + (c0 ^ 32)];           \
    }

// one quadrant's MFMA cluster: 4m x 2n x 2k
#define MFMA16(AF, BF, mh, nh)                                                 \
    __builtin_amdgcn_s_setprio(1);                                             \
    _Pragma("unroll")                                                          \
    for (int m = 0; m < 4; ++m)                                                \
        _Pragma("unroll")                                                      \
        for (int n = 0; n < 2; ++n) {                                          \
            acc[(mh) * 4 + m][(nh) * 2 + n] =                                  \
                __builtin_amdgcn_mfma_f32_16x16x32_f16(                        \
                    AF[m][0], BF[n][0], acc[(mh) * 4 + m][(nh) * 2 + n],       \
                    0, 0, 0);                                                  \
            acc[(mh) * 4 + m][(nh) * 2 + n] =                                  \
                __builtin_amdgcn_mfma_f32_16x16x32_f16(                        \
                    AF[m][1], BF[n][1], acc[(mh) * 4 + m][(nh) * 2 + n],       \
                    0, 0, 0);                                                  \
        }                                                                      \
    __builtin_amdgcn_s_setprio(0);

// one K-tile: compute buf d, stage K-tile ktn into buf e (zigzag, 4 phases)
#define KTILE(d, e, ktn)                                                       \
    {                                                                          \
        const int dbase = (d) * 16384;                                         \
        half8 af[4][2], bf0[2][2], bf1[2][2];                                  \
        /* P0: open buf d; reads af(mh0)+bf0; MFMA (0,0) */                    \
        STAGE_A(e, 0, ktn);                                                    \
        VMCNT2();                                                              \
        BARRIER();                                                             \
        RD_A(af, dbase, 0)                                                     \
        RD_B(bf0, dbase, 0)                                                    \
        MFMA16(af, bf0, 0, 0)                                                  \
        BARRIER();                                                             \
        /* P1: read bf1; MFMA (0,1) reusing af */                              \
        RD_B(bf1, dbase, 1)                                                    \
        STAGE_A(e, 1, ktn);                                                    \
        BARRIER();                                                             \
        MFMA16(af, bf1, 0, 1)                                                  \
        BARRIER();                                                             \
        /* P2: read af(mh1); MFMA (1,1) reusing bf1 */                         \
        RD_A(af, dbase, 1)                                                     \
        STAGE_B(e, 0, ktn);                                                    \
        BARRIER();                                                             \
        MFMA16(af, bf1, 1, 1)                                                  \
        BARRIER();                                                             \
        /* P3: no reads; MFMA (1,0) reusing af + still-live bf0 */             \
        STAGE_B(e, 1, ktn);                                                    \
        BARRIER();                                                             \
        MFMA16(af, bf0, 1, 0)                                                  \
        BARRIER();                                                             \
    }

__global__ __launch_bounds__(512, 2)
void gemm_f16_8ph(const _Float16* __restrict__ x16,  // [M,K] f16
                  const _Float16* __restrict__ wt,   // [N,K] f16
                  const float* __restrict__ bias,    // [N] f32
                  float* __restrict__ out)           // [M,N] f32
{
    __shared__ alignas(16) _Float16 Ash[2 * 256 * 64];   // 64 KiB
    __shared__ alignas(16) _Float16 Bsh[2 * 256 * 64];   // 64 KiB

    const int tid  = threadIdx.x;        // 0..511
    const int lane = tid & 63;
    const int wave = tid >> 6;           // 0..7
    const int wm   = wave >> 2;          // 0..1 : M half (128 rows)
    const int wn   = wave & 3;           // 0..3 : N quarter (64 cols)
    const int l15  = lane & 15;
    const int l4   = lane >> 4;

    // bijective XCD swizzle (nwg % 8 == 0): each XCD gets a contiguous chunk,
    // n-fast within chunk -> A-panel (2 MB) reused 16x in the XCD's L2.
    const int nwg = gridDim.x;
    const int lin = blockIdx.x;
    const int wg  = (lin & 7) * (nwg >> 3) + (lin >> 3);
    const int blockN = (wg & 15) * 256;
    const int blockM = (wg >> 4) * 256;

    floatx4 acc[8][4] = {};

    // ---- staging geometry: thread t covers row r*64 + (t>>3), phys chunk t&7,
    //      logical chunk (t&7)^((t>>3)&7)  (row&7 == (t>>3)&7) ----
    const int srow = tid >> 3;                         // 0..63
    const int lchk = (tid & 7) ^ ((tid >> 3) & 7);
    const _Float16* aS = x16 + (size_t)(blockM + srow) * K_IN + lchk * 8;
    const _Float16* bS = wt  + (size_t)(blockN + srow) * K_IN + lchk * 8;
    _Float16* ashW = &Ash[wave * 512];                 // wave-uniform dest base
    _Float16* bshW = &Bsh[wave * 512];

    // ---- ds_read geometry: frag (row = base + l15, logical chunk s*4 + l4),
    //      phys chunk = (s*4 + l4) ^ (l15&7); elem offset c0 (s=0), c0^32 (s=1)
    const int aRow = (wm * 128 + l15) * 64;
    const int bRow = (wn * 64 + l15) * 64;
    const int c0   = (l4 ^ (l15 & 7)) * 8;

    // ---- prologue: stage kt=0 fully into buf0 (8 loads) ----
    STAGE_A(0, 0, 0);
    STAGE_A(0, 1, 0);
    STAGE_B(0, 0, 0);
    STAGE_B(0, 1, 0);

    for (int i = 0; i < 32; ++i) {
        const int kt1 = 2 * i + 1;
        const int kt2 = (2 * i + 2 < 64) ? 2 * i + 2 : 63;  // clamped restage

        KTILE(0, 1, kt1)    // compute kt=2i   (buf0), stage kt1 -> buf1
        KTILE(1, 0, kt2)    // compute kt=2i+1 (buf1), stage kt2 -> buf0
    }

    // ---- epilogue: C frag layout col=lane&15, row=(lane>>4)*4+reg ----
#pragma unroll
    for (int n = 0; n < 4; ++n) {
        const int col = blockN + wn * 64 + n * 16 + l15;
        const float bv = bias[col];
#pragma unroll
        for (int m = 0; m < 8; ++m) {
            const int row = blockM + wm * 128 + m * 16 + l4 * 4;
#pragma unroll
            for (int r = 0; r < 4; ++r)
                out[(size_t)(row + r) * N_OUT + col] = acc[m][n][r] + bv;
        }
    }
}

// ---------------- fallback: verified fused kernel (ws too small) --------------
#define BM 128
#define BN 128
__global__ __launch_bounds__(256, 2)
void gptq_gemm_fused(const float* __restrict__ x,
                     const int*   __restrict__ qweight,
                     const int*   __restrict__ qzeros,
                     const float* __restrict__ scales,
                     const float* __restrict__ bias,
                     float*       __restrict__ out)
{
#define LDA 40
    __shared__ alignas(16) _Float16 Asf[2][BM * LDA];

    const int tid  = threadIdx.x;
    const int lane = tid & 63;
    const int wave = tid >> 6;
    const int l15  = lane & 15;
    const int l4   = lane >> 4;

    const int blockN = blockIdx.x * BN;
    const int blockM = blockIdx.y * BM;

    floatx4 acc[8][2] = {};

    const int srow = tid >> 2;
    const int sch  = tid & 3;
    const float* xr0 = x + (size_t)(blockM + srow) * K_IN + sch * 8;
    const float* xr1 = xr0 + (size_t)64 * K_IN;
    _Float16* lw0 = &Asf[0][srow * LDA + sch * 8];
    _Float16* lw1 = &Asf[0][(srow + 64) * LDA + sch * 8];

    int ncol[2];
#pragma unroll
    for (int j = 0; j < 2; ++j) ncol[j] = blockN + wave * 32 + j * 16 + l15;

    unsigned int zraw[2]; float sraw[2];
#pragma unroll
    for (int j = 0; j < 2; ++j) {
        zraw[j] = (unsigned int)qzeros[ncol[j] >> 3];
        sraw[j] = scales[ncol[j]];
    }
    float4 pa0 = *(const float4*)(xr0);
    float4 pa1 = *(const float4*)(xr0 + 4);
    float4 pb0 = *(const float4*)(xr1);
    float4 pb1 = *(const float4*)(xr1 + 4);
    unsigned int pq[2];
    {
        const int* qr = qweight + (size_t)l4 * N_OUT;
#pragma unroll
        for (int j = 0; j < 2; ++j) pq[j] = (unsigned int)qr[ncol[j]];
    }

    for (int g = 0; g < NGROUPS; ++g) {
        unsigned int c2u[2], s2u[2];
#pragma unroll
        for (int j = 0; j < 2; ++j) {
            const unsigned int z  = (zraw[j] >> ((ncol[j] & 7) * 4)) & 0xFu;
            const unsigned int cb = 0x6400u + z + 1u;
            c2u[j] = cb | (cb << 16);
            s2u[j] = pkcvt(sraw[j], sraw[j]);
        }
        const int gn = (g + 1 < NGROUPS) ? g + 1 : g;
#pragma unroll
        for (int j = 0; j < 2; ++j) {
            zraw[j] = (unsigned int)qzeros[gn * (N_OUT / 8) + (ncol[j] >> 3)];
            sraw[j] = scales[gn * N_OUT + ncol[j]];
        }

#pragma unroll
        for (int kk = 0; kk < 4; ++kk) {
            const int t   = g * 4 + kk;
            const int buf = t & 1;

            uint4 ra, rb;
            ra.x = pkcvt(pa0.x, pa1.x);  ra.y = pkcvt(pa0.y, pa1.y);
            ra.z = pkcvt(pa0.z, pa1.z);  ra.w = pkcvt(pa0.w, pa1.w);
            rb.x = pkcvt(pb0.x, pb1.x);  rb.y = pkcvt(pb0.y, pb1.y);
            rb.z = pkcvt(pb0.z, pb1.z);  rb.w = pkcvt(pb0.w, pb1.w);
            *(uint4*)(void*)(lw0 + buf * (BM * LDA)) = ra;
            *(uint4*)(void*)(lw1 + buf * (BM * LDA)) = rb;

            unsigned int bq[2] = {pq[0], pq[1]};

            const int t1 = (t + 1 < 4 * NGROUPS) ? t + 1 : t;
            pa0 = *(const float4*)(xr0 + t1 * 32);
            pa1 = *(const float4*)(xr0 + t1 * 32 + 4);
            pb0 = *(const float4*)(xr1 + t1 * 32);
            pb1 = *(const float4*)(xr1 + t1 * 32 + 4);
            {
                const int* qr = qweight + (size_t)(t1 * 4 + l4) * N_OUT;
#pragma unroll
                for (int j = 0; j < 2; ++j) pq[j] = (unsigned int)qr[ncol[j]];
            }

            __syncthreads();

            half8 bfrag[2];
#pragma unroll
            for (int j = 0; j < 2; ++j) {
                const unsigned int q = bq[j];
                const unsigned int r0 = (q & 0x000F000Fu)        | 0x64006400u;
                const unsigned int r1 = ((q >> 4) & 0x000F000Fu) | 0x64006400u;
                const unsigned int r2 = ((q >> 8) & 0x000F000Fu) | 0x64006400u;
                const unsigned int r3 = ((q >> 12) & 0x000F000Fu)| 0x64006400u;
                const half2v c2 = __builtin_bit_cast(half2v, c2u[j]);
                const half2v s2 = __builtin_bit_cast(half2v, s2u[j]);
                union { unsigned int u[4]; half8 h; } pk;
                pk.u[0] = __builtin_bit_cast(unsigned int,
                          (half2v)((__builtin_bit_cast(half2v, r0) - c2) * s2));
                pk.u[1] = __builtin_bit_cast(unsigned int,
                          (half2v)((__builtin_bit_cast(half2v, r1) - c2) * s2));
                pk.u[2] = __builtin_bit_cast(unsigned int,
                          (half2v)((__builtin_bit_cast(half2v, r2) - c2) * s2));
                pk.u[3] = __builtin_bit_cast(unsigned int,
                          (half2v)((__builtin_bit_cast(half2v, r3) - c2) * s2));
                bfrag[j] = pk.h;
            }

            half8 afrag[8];
#pragma unroll
            for (int i = 0; i < 8; ++i)
                afrag[i] = *(const half8*)(const void*)
                    &Asf[buf][(i * 16 + l15) * LDA + l4 * 8];

#pragma unroll
            for (int i = 0; i < 8; ++i)
#pragma unroll
                for (int j = 0; j < 2; ++j)
                    acc[i][j] = __builtin_amdgcn_mfma_f32_16x16x32_f16(
                        afrag[i], bfrag[j], acc[i][j], 0, 0, 0);
        }
    }

#pragma unroll
    for (int j = 0; j < 2; ++j) {
        const int n = ncol[j];
        const float bv = bias[n];
#pragma unroll
        for (int i = 0; i < 8; ++i) {
            const int m = blockM + i * 16 + l4 * 4;
#pragma unroll
            for (int r = 0; r < 4; ++r)
                out[(size_t)(m + r) * N_OUT + n] = acc[i][j][r] + bv;
        }
    }
#undef LDA
}

extern "C" void kernel_launch(void* const* d_in, const int* in_sizes, int n_in,
                              void* d_out, int out_size, void* d_ws, size_t ws_size,
                              hipStream_t stream) {
    const float* x    = (const float*)d_in[0];
    const int*   qw   = (const int*)d_in[1];
    const int*   qz   = (const int*)d_in[2];
    const float* sc   = (const float*)d_in[3];
    const float* bias = (const float*)d_in[4];
    float*       out  = (float*)d_out;

    const int M = in_sizes[0] / K_IN;   // 8192

    const size_t x16_bytes = (size_t)M * K_IN * sizeof(_Float16);
    const size_t wt_bytes  = (size_t)N_OUT * K_IN * sizeof(_Float16);

    if (ws_size >= x16_bytes + wt_bytes && (M % 256) == 0) {
        _Float16* x16 = (_Float16*)d_ws;
        _Float16* wtp = (_Float16*)((char*)d_ws + x16_bytes);

        cvt_x_f16<<<(int)((size_t)M * K_IN / 2048), 256, 0, stream>>>(x, x16);
        dequant_wt<<<dim3(N_OUT / 64, NGROUPS), 256, 0, stream>>>(qw, qz, sc, wtp);
        const int nwg = (M / 256) * (N_OUT / 256);   // 512; % 8 == 0
        gemm_f16_8ph<<<nwg, 512, 0, stream>>>(x16, wtp, bias, out);
    } else {
        gptq_gemm_fused<<<dim3(N_OUT / BN, M / BM), 256, 0, stream>>>(
            x, qw, qz, sc, bias, out);
    }
}